// Round 1
// baseline (894.615 us; speedup 1.0000x reference)
//
#include <hip/hip_runtime.h>

// Problem constants (from reference)
constexpr int XD = 32;                 // x_dim
constexpr int YD = 32;                 // y_dim
constexpr int HD = 128;                // hidden dim
constexpr int NL = 4;                  // layers
constexpr int W0_SIZE = (XD + 1) * HD;                         // 4224
constexpr int WI_SIZE = HD * HD;                               // 16384
constexpr int WL_OFF  = W0_SIZE + (NL - 2) * WI_SIZE;          // 36992
constexpr int ZD      = WL_OFF + HD * YD;                      // 41088
constexpr int SDIM = 128, BDIM = 32;
constexpr int NPAIR = SDIM * BDIM;                             // 4096

// One block (128 threads) per (s,b) pair.
// thread = (part = tid>>5 in [0,4), jq = tid&31 in [0,32))
// Middle layers: part owns rows [part*32, part*32+32); thread accumulates a
// float4 of output columns [4*jq, 4*jq+4). 16B/lane coalesced global loads.
__global__ __launch_bounds__(128, 8)
void mlp_hyper_kernel(const float* __restrict__ x,
                      const float* __restrict__ z,
                      float* __restrict__ out) {
    const int pair = blockIdx.x;
    const int tid  = threadIdx.x;
    const int part = tid >> 5;
    const int jq   = tid & 31;

    const float* __restrict__ zb = z + (size_t)pair * ZD;
    const float* __restrict__ xb = x + (size_t)pair * XD;

    __shared__ float xs[XD + 1];
    __shared__ float ybuf[HD];
    __shared__ float pacc[4][HD];

    if (tid <= XD) xs[tid] = (tid < XD) ? xb[tid] : 1.0f;
    __syncthreads();

    // ---- layer 0: (33 x 128), rows split 8 per part (+ bias row -> part 0) ----
    {
        float4 a = make_float4(0.f, 0.f, 0.f, 0.f);
        #pragma unroll
        for (int r = 0; r < 8; ++r) {
            const int i = part * 8 + r;
            const float xv = xs[i];
            const float4 w = *reinterpret_cast<const float4*>(zb + (size_t)i * HD + 4 * jq);
            a.x += xv * w.x; a.y += xv * w.y; a.z += xv * w.z; a.w += xv * w.w;
        }
        if (part == 0) {  // bias row (x_aug[32] == 1)
            const float4 w = *reinterpret_cast<const float4*>(zb + (size_t)XD * HD + 4 * jq);
            a.x += w.x; a.y += w.y; a.z += w.z; a.w += w.w;
        }
        *reinterpret_cast<float4*>(&pacc[part][4 * jq]) = a;
    }
    __syncthreads();
    {
        const float v = pacc[0][tid] + pacc[1][tid] + pacc[2][tid] + pacc[3][tid];
        ybuf[tid] = fmaxf(v, 0.f);
    }
    __syncthreads();

    // ---- middle layers: (128 x 128) x (NL-2) ----
    #pragma unroll
    for (int l = 0; l < NL - 2; ++l) {
        const float* __restrict__ w = zb + W0_SIZE + (size_t)l * WI_SIZE;
        float4 a = make_float4(0.f, 0.f, 0.f, 0.f);
        #pragma unroll
        for (int r = 0; r < 32; ++r) {
            const int i = part * 32 + r;
            const float yv = ybuf[i];
            const float4 wv = *reinterpret_cast<const float4*>(w + (size_t)i * HD + 4 * jq);
            a.x += yv * wv.x; a.y += yv * wv.y; a.z += yv * wv.z; a.w += yv * wv.w;
        }
        *reinterpret_cast<float4*>(&pacc[part][4 * jq]) = a;
        __syncthreads();
        const float v = pacc[0][tid] + pacc[1][tid] + pacc[2][tid] + pacc[3][tid];
        ybuf[tid] = fmaxf(v, 0.f);
        __syncthreads();
    }

    // ---- last layer: (128 x 32), no relu ----
    {
        const float* __restrict__ w3 = zb + WL_OFF;
        float a = 0.f;
        #pragma unroll
        for (int r = 0; r < 32; ++r) {
            const int i = part * 32 + r;
            a += ybuf[i] * w3[(size_t)i * YD + jq];
        }
        pacc[part][jq] = a;
    }
    __syncthreads();
    if (tid < YD) {
        out[(size_t)pair * YD + tid] =
            pacc[0][tid] + pacc[1][tid] + pacc[2][tid] + pacc[3][tid];
    }
}

extern "C" void kernel_launch(void* const* d_in, const int* in_sizes, int n_in,
                              void* d_out, int out_size, void* d_ws, size_t ws_size,
                              hipStream_t stream) {
    const float* x = (const float*)d_in[0];
    const float* z = (const float*)d_in[1];
    float* out = (float*)d_out;
    mlp_hyper_kernel<<<dim3(NPAIR), dim3(128), 0, stream>>>(x, z, out);
}